// Round 6
// baseline (4630.679 us; speedup 1.0000x reference)
//
#include <hip/hip_runtime.h>

#define NP_   16384
#define NQ_   8192
#define NB_   2
#define K_    16
#define SPLIT 16
#define QPB   16          // queries per block
#define TPB   256
#define TILE  1024        // points per LDS tile
#define NTILES (NP_/TILE) // 16
#define CBUF  8           // per-thread overflow buffer entries
#define JPT   (TILE/SPLIT) // 64 candidates per thread per tile

#define IDX_OFF 0
#define RS_OFF  (NB_*NQ_*K_)        // 262144
#define RS_N    (NB_*NQ_+1)         // 16385
#define DST_OFF (RS_OFF + RS_N)     // 278529

__global__ __launch_bounds__(TPB) void knn_kernel(const float* __restrict__ pts,
                                                  const float* __restrict__ qrs,
                                                  float* __restrict__ out)
{
    // Match the np reference bit-exactly:
    //   sq, sp : forward sum, separate mul/add rounds (np.sum pairwise, n<8)
    //   ip     : forward FMA chain (BLAS sgemm microkernel: acc=fma(ak,bk,acc))
    //   d      : (sq + sp) - 2*ip, separate rounds (elementwise ufuncs)
    #pragma clang fp contract(off)

    __shared__ union SmemU {
        struct { float4 tile[TILE]; float2 buf[CBUF][TPB]; } a;  // 16KB + 16KB
        float2 merge[K_][TPB];                                    // 32KB
    } sm;

    const int tid = threadIdx.x;
    const int s   = tid & (SPLIT - 1);
    const int ql  = tid >> 4;                  // 0..15
    const int gq  = blockIdx.x * QPB + ql;     // 0..16383
    const int batch = gq >> 13;                // / 8192
    const int gofs  = batch * NP_;
    const float* pb = pts + (size_t)gofs * 3;

    const float qx = qrs[gq*3+0], qy = qrs[gq*3+1], qz = qrs[gq*3+2];
    const float sq = qx*qx + qy*qy + qz*qz;    // fwd, no FMA (contract off)

    float ad[K_]; int ai[K_];
    #pragma unroll
    for (int i = 0; i < K_; ++i) { ad[i] = __int_as_float(0x7f800000); ai[i] = 0x7fffffff; }
    float worst = __int_as_float(0x7f800000);
    int cnt = 0;

    auto compact = [&]() {
        for (int m = 0; m < cnt; ++m) {
            float2 e = sm.a.buf[m][tid];
            float d = e.x; int gi = __float_as_int(e.y);
            if (d < ad[K_-1]) {                 // fresh-threshold check
                ad[K_-1] = d; ai[K_-1] = gi;    // bubble single out-of-place elem
                #pragma unroll
                for (int i = K_-1; i > 0; --i) {
                    bool sw = ad[i] < ad[i-1];  // strict: stable on ties
                    float td = ad[i-1]; int ti = ai[i-1];
                    ad[i-1] = sw ? ad[i] : td;  ai[i-1] = sw ? ai[i] : ti;
                    ad[i]   = sw ? td   : ad[i]; ai[i]  = sw ? ti   : ai[i];
                }
            }
        }
        cnt = 0;
        worst = ad[K_-1];
    };

    for (int t = 0; t < NTILES; ++t) {
        __syncthreads();
        // stage 1024 points -> LDS as (x,y,z,|p|^2)
        #pragma unroll
        for (int k = 0; k < TILE/TPB; ++k) {
            int lp = tid + k*TPB;
            int gp = t*TILE + lp;
            float x = pb[gp*3+0], y = pb[gp*3+1], z = pb[gp*3+2];
            float sp = x*x + y*y + z*z;         // fwd, no FMA (contract off)
            sm.a.tile[lp] = make_float4(x, y, z, sp);
        }
        __syncthreads();
        // scan: thread handles candidates  j*16 + s  (ascending index => stable)
        #pragma unroll 4
        for (int j = 0; j < JPT; ++j) {
            float4 p = sm.a.tile[j*SPLIT + s];
            // ip: forward FMA chain (sgemm): fma(z,qz, fma(y,qy, round(x*qx)))
            float ip = fmaf(p.z, qz, fmaf(p.y, qy, __fmul_rn(p.x, qx)));
            // combine: (sq + sp) - 2*ip, separate rounds (2*ip exact)
            float d  = (sq + p.w) - 2.0f*ip;
            if (d < worst) {
                sm.a.buf[cnt][tid] = make_float2(d, __int_as_float(t*TILE + j*SPLIT + s));
                if (++cnt == CBUF) compact();
            }
        }
    }
    compact();            // flush remainder (cnt may be 0)

    __syncthreads();      // scan done; reuse LDS for merge lists
    #pragma unroll
    for (int m = 0; m < K_; ++m)
        sm.merge[m][tid] = make_float2(ad[m], __int_as_float(ai[m]));
    __syncthreads();

    // 16-way merge of 16 sorted lists per query via width-16 shfl min-reduce
    int pos = 1;
    float hd = ad[0]; int hi = ai[0];
    float rd = 0.0f;  int ri = 0;
    #pragma unroll
    for (int r = 0; r < K_; ++r) {
        float bd = hd; int bi = hi; int bl = s;
        #pragma unroll
        for (int off = 8; off >= 1; off >>= 1) {
            float od = __shfl_xor(bd, off, SPLIT);
            int   oi = __shfl_xor(bi, off, SPLIT);
            int   ol = __shfl_xor(bl, off, SPLIT);
            bool take = (od < bd) || (od == bd && oi < bi);   // lexicographic: stable
            bd = take ? od : bd; bi = take ? oi : bi; bl = take ? ol : bl;
        }
        if (r == s) { rd = bd; ri = bi; }     // lane s keeps rank-s result
        if (bl == s) {                        // winner advances its head
            if (pos < K_) { float2 e = sm.merge[pos][tid]; hd = e.x; hi = __float_as_int(e.y); ++pos; }
            else { hd = __int_as_float(0x7f800000); hi = 0x7fffffff; }
        }
    }

    // coalesced output: lane s writes rank-s neighbor of its query
    out[IDX_OFF + gq*K_ + s] = (float)(ri + gofs);
    out[DST_OFF + gq*K_ + s] = fmaxf(rd, 0.0f);

    // row_splits = arange(16385) * 16, written as float (exact)
    int gt = blockIdx.x * TPB + tid;
    if (gt < RS_N) out[RS_OFF + gt] = (float)(gt * K_);
}

extern "C" void kernel_launch(void* const* d_in, const int* in_sizes, int n_in,
                              void* d_out, int out_size, void* d_ws, size_t ws_size,
                              hipStream_t stream)
{
    const float* pts = (const float*)d_in[0];
    const float* qrs = (const float*)d_in[1];
    float* out = (float*)d_out;
    (void)in_sizes; (void)n_in; (void)out_size; (void)d_ws; (void)ws_size;

    dim3 grid(NB_ * NQ_ / QPB);   // 1024 blocks
    dim3 block(TPB);              // 256 threads
    knn_kernel<<<grid, block, 0, stream>>>(pts, qrs, out);
}

// Round 7
// 1078.146 us; speedup vs baseline: 4.2950x; 4.2950x over previous
//
#include <hip/hip_runtime.h>

#define NP_   16384
#define NQ_   8192
#define NB_   2
#define K_    16
#define SPLIT 16
#define QPB   16          // queries per block
#define TPB   256
#define TILE  1024        // points per LDS tile
#define NTILES (NP_/TILE) // 16
#define CBUF  8           // per-thread overflow buffer entries
#define JPT   (TILE/SPLIT) // 64 candidates per thread per tile
#define SEEDJ 16          // first 16 candidates per lane: uniform (divergence-free) inserts

#define IDX_OFF 0
#define RS_OFF  (NB_*NQ_*K_)        // 262144
#define RS_N    (NB_*NQ_+1)         // 16385
#define DST_OFF (RS_OFF + RS_N)     // 278529

__global__ __launch_bounds__(TPB) void knn_kernel(const float* __restrict__ pts,
                                                  const float* __restrict__ qrs,
                                                  float* __restrict__ out)
{
    // Validated exact-match formula (R6):
    //   sq, sp : forward sum, separate mul/add rounds
    //   ip     : forward FMA chain  fma(z,qz, fma(y,qy, round(x*qx)))
    //   d      : (sq + sp) - 2*ip, separate rounds
    #pragma clang fp contract(off)

    __shared__ union SmemU {
        struct { float4 tile[TILE]; float2 buf[CBUF][TPB]; } a;  // 16KB + 16KB
        float2 merge[K_][TPB];                                    // 32KB
    } sm;

    const int tid = threadIdx.x;
    const int s   = tid & (SPLIT - 1);
    const int ql  = tid >> 4;                  // 0..15
    const int gq  = blockIdx.x * QPB + ql;     // 0..16383
    const int batch = gq >> 13;                // / 8192
    const int gofs  = batch * NP_;
    const float* pb = pts + (size_t)gofs * 3;

    const float qx = qrs[gq*3+0], qy = qrs[gq*3+1], qz = qrs[gq*3+2];
    const float sq = qx*qx + qy*qy + qz*qz;    // fwd, no FMA (contract off)

    float ad[K_]; int ai[K_];
    #pragma unroll
    for (int i = 0; i < K_; ++i) { ad[i] = __int_as_float(0x7f800000); ai[i] = 0x7fffffff; }
    int cnt = 0;

    // sorted insert; guard (d < ad[15]) is ALWAYS true for the first 16 calls
    // per lane (ad[15]=+inf) -> uniform control flow during seeding.
    auto insert1 = [&](float d, int gi) {
        if (d < ad[K_-1]) {
            ad[K_-1] = d; ai[K_-1] = gi;
            #pragma unroll
            for (int i = K_-1; i > 0; --i) {
                bool sw = ad[i] < ad[i-1];      // strict: stable on ties
                float td = ad[i-1]; int ti = ai[i-1];
                ad[i-1] = sw ? ad[i] : td;  ai[i-1] = sw ? ai[i] : ti;
                ad[i]   = sw ? td   : ad[i]; ai[i]  = sw ? ti   : ai[i];
            }
        }
    };

    auto compact = [&]() {                      // called wave-uniformly per tile
        for (int m = 0; m < cnt; ++m) {
            float2 e = sm.a.buf[m][tid];
            insert1(e.x, __float_as_int(e.y));
        }
        cnt = 0;
    };

    // shared per-query pruning bound: min over the query's 16 lanes of each
    // lane's own 16th-best = upper bound on the query's true 16th-best.
    // Filter key == final key (exact), so `d <= thresh` keeps every final
    // top-16 member (ties at rank 16 included).
    auto qmin16 = [&](float w) {
        #pragma unroll
        for (int off = 8; off >= 1; off >>= 1)
            w = fminf(w, __shfl_xor(w, off, SPLIT));
        return w;
    };

    float thresh = 0.0f;

    for (int t = 0; t < NTILES; ++t) {
        __syncthreads();
        #pragma unroll
        for (int k = 0; k < TILE/TPB; ++k) {
            int lp = tid + k*TPB;
            int gp = t*TILE + lp;
            float x = pb[gp*3+0], y = pb[gp*3+1], z = pb[gp*3+2];
            float sp = x*x + y*y + z*z;         // fwd, no FMA
            sm.a.tile[lp] = make_float4(x, y, z, sp);
        }
        __syncthreads();

        int jlo = 0;
        if (t == 0) {
            // seed: first SEEDJ candidates/lane always insert (no divergence)
            for (int j = 0; j < SEEDJ; ++j) {
                float4 p = sm.a.tile[j*SPLIT + s];
                float ip = fmaf(p.z, qz, fmaf(p.y, qy, __fmul_rn(p.x, qx)));
                float d  = (sq + p.w) - 2.0f*ip;
                insert1(d, j*SPLIT + s);
            }
            thresh = qmin16(ad[K_-1]);          // all finite now
            jlo = SEEDJ;
        }

        // filtered scan: append (d, idx); compact deferred to tile boundary
        #pragma unroll 4
        for (int j = jlo; j < JPT; ++j) {
            float4 p = sm.a.tile[j*SPLIT + s];
            float ip = fmaf(p.z, qz, fmaf(p.y, qy, __fmul_rn(p.x, qx)));
            float d  = (sq + p.w) - 2.0f*ip;
            if (d <= thresh) {
                sm.a.buf[cnt][tid] = make_float2(d, __int_as_float(t*TILE + j*SPLIT + s));
                if (++cnt == CBUF) compact();   // valve only; ~never fires
            }
        }

        compact();                              // wave-uniform
        thresh = qmin16(ad[K_-1]);
    }

    __syncthreads();      // scan done; reuse LDS for merge lists
    #pragma unroll
    for (int m = 0; m < K_; ++m)
        sm.merge[m][tid] = make_float2(ad[m], __int_as_float(ai[m]));
    __syncthreads();

    // 16-way merge of 16 sorted lists per query via width-16 shfl min-reduce
    int pos = 1;
    float hd = ad[0]; int hi = ai[0];
    float rd = 0.0f;  int ri = 0;
    #pragma unroll
    for (int r = 0; r < K_; ++r) {
        float bd = hd; int bi = hi; int bl = s;
        #pragma unroll
        for (int off = 8; off >= 1; off >>= 1) {
            float od = __shfl_xor(bd, off, SPLIT);
            int   oi = __shfl_xor(bi, off, SPLIT);
            int   ol = __shfl_xor(bl, off, SPLIT);
            bool take = (od < bd) || (od == bd && oi < bi);   // lexicographic: stable
            bd = take ? od : bd; bi = take ? oi : bi; bl = take ? ol : bl;
        }
        if (r == s) { rd = bd; ri = bi; }     // lane s keeps rank-s result
        if (bl == s) {                        // winner advances its head
            if (pos < K_) { float2 e = sm.merge[pos][tid]; hd = e.x; hi = __float_as_int(e.y); ++pos; }
            else { hd = __int_as_float(0x7f800000); hi = 0x7fffffff; }
        }
    }

    // coalesced output: lane s writes rank-s neighbor of its query
    out[IDX_OFF + gq*K_ + s] = (float)(ri + gofs);
    out[DST_OFF + gq*K_ + s] = fmaxf(rd, 0.0f);

    // row_splits = arange(16385) * 16, written as float (exact)
    int gt = blockIdx.x * TPB + tid;
    if (gt < RS_N) out[RS_OFF + gt] = (float)(gt * K_);
}

extern "C" void kernel_launch(void* const* d_in, const int* in_sizes, int n_in,
                              void* d_out, int out_size, void* d_ws, size_t ws_size,
                              hipStream_t stream)
{
    const float* pts = (const float*)d_in[0];
    const float* qrs = (const float*)d_in[1];
    float* out = (float*)d_out;
    (void)in_sizes; (void)n_in; (void)out_size; (void)d_ws; (void)ws_size;

    dim3 grid(NB_ * NQ_ / QPB);   // 1024 blocks
    dim3 block(TPB);              // 256 threads
    knn_kernel<<<grid, block, 0, stream>>>(pts, qrs, out);
}

// Round 8
// 319.223 us; speedup vs baseline: 14.5061x; 3.3774x over previous
//
#include <hip/hip_runtime.h>

#define NP_   16384
#define NQ_   8192
#define NB_   2
#define K_    16
#define SPLIT 16
#define QPB   16          // queries per block
#define TPB   256
#define TILE  1024        // points per LDS tile
#define NTILES (NP_/TILE) // 16
#define CHUNK 8           // candidates per lane per chunk == CBUF (no overflow possible)
#define CBUF  8
#define NCHUNK (TILE/SPLIT/CHUNK) // 8 chunks per tile

#define IDX_OFF 0
#define RS_OFF  (NB_*NQ_*K_)        // 262144
#define RS_N    (NB_*NQ_+1)         // 16385
#define DST_OFF (RS_OFF + RS_N)     // 278529

__global__ __launch_bounds__(TPB, 4) void knn_kernel(const float* __restrict__ pts,
                                                     const float* __restrict__ qrs,
                                                     float* __restrict__ out)
{
    // Validated exact-match formula (R6):
    //   sq, sp : forward sum, separate mul/add rounds
    //   ip     : forward FMA chain  fma(z,qz, fma(y,qy, round(x*qx)))
    //   d      : (sq + sp) - 2*ip, separate rounds
    #pragma clang fp contract(off)

    __shared__ union SmemU {
        struct { float4 tile[TILE]; float2 buf[CBUF][TPB]; } a;  // 16KB + 16KB
        float2 merge[K_][TPB];                                    // 32KB
    } sm;

    const int tid = threadIdx.x;
    const int s   = tid & (SPLIT - 1);
    const int ql  = tid >> 4;                  // 0..15
    const int gq  = blockIdx.x * QPB + ql;     // 0..16383
    const int batch = gq >> 13;                // / 8192
    const int gofs  = batch * NP_;
    const float* pb = pts + (size_t)gofs * 3;

    const float qx = qrs[gq*3+0], qy = qrs[gq*3+1], qz = qrs[gq*3+2];
    const float sq = qx*qx + qy*qy + qz*qz;    // fwd, no FMA (contract off)

    const float INF = __int_as_float(0x7f800000);
    float ad[K_]; int ai[K_];
    #pragma unroll
    for (int i = 0; i < K_; ++i) { ad[i] = INF; ai[i] = 0x7fffffff; }

    float thresh = INF;   // chunk 0 appends everything; finite after 2 chunks

    for (int t = 0; t < NTILES; ++t) {
        __syncthreads();
        #pragma unroll
        for (int k = 0; k < TILE/TPB; ++k) {
            int lp = tid + k*TPB;
            int gp = t*TILE + lp;
            float x = pb[gp*3+0], y = pb[gp*3+1], z = pb[gp*3+2];
            float sp = x*x + y*y + z*z;         // fwd, no FMA
            sm.a.tile[lp] = make_float4(x, y, z, sp);
        }
        __syncthreads();

        for (int c = 0; c < NCHUNK; ++c) {
            // ---- scan 8 candidates/lane; appends bounded by CHUNK==CBUF ----
            int cnt = 0;
            #pragma unroll
            for (int jj = 0; jj < CHUNK; ++jj) {
                int j = c*CHUNK + jj;
                float4 p = sm.a.tile[j*SPLIT + s];
                float ip = fmaf(p.z, qz, fmaf(p.y, qy, __fmul_rn(p.x, qx)));
                float d  = (sq + p.w) - 2.0f*ip;
                if (d <= thresh) {
                    sm.a.buf[cnt][tid] = make_float2(d, __int_as_float(t*TILE + j*SPLIT + s));
                    ++cnt;                       // cnt <= CHUNK structurally
                }
            }
            // ---- wave-uniform compact: merge appended into register top-16 ----
            for (int m = 0; m < cnt; ++m) {      // usually cnt == 0
                float2 e = sm.a.buf[m][tid];
                float d = e.x; int gi = __float_as_int(e.y);
                if (d < ad[K_-1]) {
                    ad[K_-1] = d; ai[K_-1] = gi;
                    #pragma unroll
                    for (int i = K_-1; i > 0; --i) {
                        bool sw = ad[i] < ad[i-1];      // strict: stable on ties
                        float td = ad[i-1]; int ti = ai[i-1];
                        ad[i-1] = sw ? ad[i] : td;  ai[i-1] = sw ? ai[i] : ti;
                        ad[i]   = sw ? td   : ad[i]; ai[i]  = sw ? ti   : ai[i];
                    }
                }
            }
            // ---- tighten shared per-query bound (upper bound on true 16th-best) ----
            float w = ad[K_-1];
            #pragma unroll
            for (int off = 8; off >= 1; off >>= 1)
                w = fminf(w, __shfl_xor(w, off, SPLIT));
            thresh = w;
        }
    }

    __syncthreads();      // scan done; reuse LDS for merge lists
    #pragma unroll
    for (int m = 0; m < K_; ++m)
        sm.merge[m][tid] = make_float2(ad[m], __int_as_float(ai[m]));
    __syncthreads();

    // 16-way merge of 16 sorted lists per query via width-16 shfl min-reduce
    int pos = 1;
    float hd = ad[0]; int hi = ai[0];
    float rd = 0.0f;  int ri = 0;
    #pragma unroll
    for (int r = 0; r < K_; ++r) {
        float bd = hd; int bi = hi; int bl = s;
        #pragma unroll
        for (int off = 8; off >= 1; off >>= 1) {
            float od = __shfl_xor(bd, off, SPLIT);
            int   oi = __shfl_xor(bi, off, SPLIT);
            int   ol = __shfl_xor(bl, off, SPLIT);
            bool take = (od < bd) || (od == bd && oi < bi);   // lexicographic: stable
            bd = take ? od : bd; bi = take ? oi : bi; bl = take ? ol : bl;
        }
        if (r == s) { rd = bd; ri = bi; }     // lane s keeps rank-s result
        if (bl == s) {                        // winner advances its head
            if (pos < K_) { float2 e = sm.merge[pos][tid]; hd = e.x; hi = __float_as_int(e.y); ++pos; }
            else { hd = __int_as_float(0x7f800000); hi = 0x7fffffff; }
        }
    }

    // coalesced output: lane s writes rank-s neighbor of its query
    out[IDX_OFF + gq*K_ + s] = (float)(ri + gofs);
    out[DST_OFF + gq*K_ + s] = fmaxf(rd, 0.0f);

    // row_splits = arange(16385) * 16, written as float (exact)
    int gt = blockIdx.x * TPB + tid;
    if (gt < RS_N) out[RS_OFF + gt] = (float)(gt * K_);
}

extern "C" void kernel_launch(void* const* d_in, const int* in_sizes, int n_in,
                              void* d_out, int out_size, void* d_ws, size_t ws_size,
                              hipStream_t stream)
{
    const float* pts = (const float*)d_in[0];
    const float* qrs = (const float*)d_in[1];
    float* out = (float*)d_out;
    (void)in_sizes; (void)n_in; (void)out_size; (void)d_ws; (void)ws_size;

    dim3 grid(NB_ * NQ_ / QPB);   // 1024 blocks
    dim3 block(TPB);              // 256 threads
    knn_kernel<<<grid, block, 0, stream>>>(pts, qrs, out);
}

// Round 9
// 230.494 us; speedup vs baseline: 20.0902x; 1.3849x over previous
//
#include <hip/hip_runtime.h>

#define NP_   16384
#define NQ_   8192
#define NB_   2
#define K_    16
#define SPLIT 16
#define QPB   16          // queries per block
#define TPB   256
#define TILE  1024        // points per LDS tile
#define NTILES (NP_/TILE) // 16
#define JPT   (TILE/SPLIT) // 64 candidates per lane per tile
#define CHUNK 8           // tile-0 cadence (threshold bootstrap)
#define CBUF  16          // per-lane append buffer (indices) per tile

#define IDX_OFF 0
#define RS_OFF  (NB_*NQ_*K_)        // 262144
#define RS_N    (NB_*NQ_+1)         // 16385
#define DST_OFF (RS_OFF + RS_N)     // 278529

__global__ __launch_bounds__(TPB, 4) void knn_kernel(const float* __restrict__ pts,
                                                     const float* __restrict__ qrs,
                                                     float* __restrict__ out)
{
    // Validated exact-match formula (R6):
    //   sq, sp : forward sum, separate mul/add rounds
    //   ip     : forward FMA chain  fma(z,qz, fma(y,qy, round(x*qx)))
    //   d      : (sq + sp) - 2*ip, separate rounds
    #pragma clang fp contract(off)

    __shared__ union SmemU {
        struct { float4 tile[TILE]; int buf[CBUF][TPB]; } a;   // 16KB + 16KB
        float2 merge[K_][TPB];                                  // 32KB
    } sm;

    const int tid = threadIdx.x;
    const int s   = tid & (SPLIT - 1);
    const int ql  = tid >> 4;                  // 0..15
    const int gq  = blockIdx.x * QPB + ql;     // 0..16383
    const int batch = gq >> 13;                // / 8192
    const int gofs  = batch * NP_;
    const float* pb = pts + (size_t)gofs * 3;

    const float qx = qrs[gq*3+0], qy = qrs[gq*3+1], qz = qrs[gq*3+2];
    const float sq = qx*qx + qy*qy + qz*qz;    // fwd, no FMA (contract off)

    const float INF = __int_as_float(0x7f800000);
    float ad[K_]; int ai[K_];
    #pragma unroll
    for (int i = 0; i < K_; ++i) { ad[i] = INF; ai[i] = 0x7fffffff; }

    // exact distance of tile-local candidate j*16+s (identical chain everywhere)
    auto dof = [&](int j) {
        float4 p = sm.a.tile[j*SPLIT + s];
        float ip = fmaf(p.z, qz, fmaf(p.y, qy, __fmul_rn(p.x, qx)));
        return (sq + p.w) - 2.0f*ip;
    };

    auto insert1 = [&](float d, int gi) {
        if (d < ad[K_-1]) {                     // strict: stable on ties
            ad[K_-1] = d; ai[K_-1] = gi;
            #pragma unroll
            for (int i = K_-1; i > 0; --i) {
                bool sw = ad[i] < ad[i-1];
                float td = ad[i-1]; int ti = ai[i-1];
                ad[i-1] = sw ? ad[i] : td;  ai[i-1] = sw ? ai[i] : ti;
                ad[i]   = sw ? td   : ad[i]; ai[i]  = sw ? ti   : ai[i];
            }
        }
    };

    auto qmin16 = [&](float w) {               // shared per-query upper bound
        #pragma unroll
        for (int off = 8; off >= 1; off >>= 1)
            w = fminf(w, __shfl_xor(w, off, SPLIT));
        return w;
    };

    float thresh = INF;

    for (int t = 0; t < NTILES; ++t) {
        __syncthreads();
        #pragma unroll
        for (int k = 0; k < TILE/TPB; ++k) {
            int lp = tid + k*TPB;
            int gp = t*TILE + lp;
            float x = pb[gp*3+0], y = pb[gp*3+1], z = pb[gp*3+2];
            float sp = x*x + y*y + z*z;         // fwd, no FMA
            sm.a.tile[lp] = make_float4(x, y, z, sp);
        }
        __syncthreads();

        if (t == 0) {
            // bootstrap: chunked cadence so thresh becomes finite w/o overflow
            for (int c = 0; c < JPT/CHUNK; ++c) {
                int cnt = 0;
                #pragma unroll
                for (int jj = 0; jj < CHUNK; ++jj) {
                    int j = c*CHUNK + jj;
                    if (dof(j) <= thresh) { sm.a.buf[cnt][tid] = j; ++cnt; }
                }
                for (int m = 0; m < cnt; ++m) {
                    int j = sm.a.buf[m][tid];
                    insert1(dof(j), j*SPLIT + s);   // t==0: gi = lidx
                }
                thresh = qmin16(ad[K_-1]);
            }
        } else {
            // ---- hot path: whole-tile scan, indices only, no valve ----
            int cnt = 0;
            #pragma unroll 8
            for (int j = 0; j < JPT; ++j) {
                if (dof(j) <= thresh) {
                    if (cnt < CBUF) sm.a.buf[cnt][tid] = j;
                    ++cnt;
                }
            }
            // overflow rescue (correctness valve; ~never taken, exec-skipped)
            if (__ballot(cnt > CBUF)) {
                if (cnt > CBUF) {
                    cnt = 0;
                    for (int j = 0; j < JPT; ++j)
                        insert1(dof(j), t*TILE + j*SPLIT + s);
                }
            }
            // ---- wave-uniform compact, once per tile ----
            for (int m = 0; m < cnt; ++m) {
                int j = sm.a.buf[m][tid];
                insert1(dof(j), t*TILE + j*SPLIT + s);
            }
            thresh = qmin16(ad[K_-1]);
        }
    }

    __syncthreads();      // scan done; reuse LDS for merge lists
    #pragma unroll
    for (int m = 0; m < K_; ++m)
        sm.merge[m][tid] = make_float2(ad[m], __int_as_float(ai[m]));
    __syncthreads();

    // 16-way merge of 16 sorted lists per query via width-16 shfl min-reduce
    int pos = 1;
    float hd = ad[0]; int hi = ai[0];
    float rd = 0.0f;  int ri = 0;
    #pragma unroll
    for (int r = 0; r < K_; ++r) {
        float bd = hd; int bi = hi; int bl = s;
        #pragma unroll
        for (int off = 8; off >= 1; off >>= 1) {
            float od = __shfl_xor(bd, off, SPLIT);
            int   oi = __shfl_xor(bi, off, SPLIT);
            int   ol = __shfl_xor(bl, off, SPLIT);
            bool take = (od < bd) || (od == bd && oi < bi);   // lexicographic: stable
            bd = take ? od : bd; bi = take ? oi : bi; bl = take ? ol : bl;
        }
        if (r == s) { rd = bd; ri = bi; }     // lane s keeps rank-s result
        if (bl == s) {                        // winner advances its head
            if (pos < K_) { float2 e = sm.merge[pos][tid]; hd = e.x; hi = __float_as_int(e.y); ++pos; }
            else { hd = __int_as_float(0x7f800000); hi = 0x7fffffff; }
        }
    }

    // coalesced output: lane s writes rank-s neighbor of its query
    out[IDX_OFF + gq*K_ + s] = (float)(ri + gofs);
    out[DST_OFF + gq*K_ + s] = fmaxf(rd, 0.0f);

    // row_splits = arange(16385) * 16, written as float (exact)
    int gt = blockIdx.x * TPB + tid;
    if (gt < RS_N) out[RS_OFF + gt] = (float)(gt * K_);
}

extern "C" void kernel_launch(void* const* d_in, const int* in_sizes, int n_in,
                              void* d_out, int out_size, void* d_ws, size_t ws_size,
                              hipStream_t stream)
{
    const float* pts = (const float*)d_in[0];
    const float* qrs = (const float*)d_in[1];
    float* out = (float*)d_out;
    (void)in_sizes; (void)n_in; (void)out_size; (void)d_ws; (void)ws_size;

    dim3 grid(NB_ * NQ_ / QPB);   // 1024 blocks
    dim3 block(TPB);              // 256 threads
    knn_kernel<<<grid, block, 0, stream>>>(pts, qrs, out);
}

// Round 10
// 190.010 us; speedup vs baseline: 24.3707x; 1.2131x over previous
//
#include <hip/hip_runtime.h>

#define NP_   16384
#define NQ_   8192
#define NB_   2
#define K_    16
#define SPLIT 16
#define QPB   16          // queries per block
#define TPB   256
#define TILE  1024        // points per LDS tile
#define NTILES (NP_/TILE) // 16
#define JPT   (TILE/SPLIT) // 64 candidates per lane per tile == bits in uint64

#define IDX_OFF 0
#define RS_OFF  (NB_*NQ_*K_)        // 262144
#define RS_N    (NB_*NQ_+1)         // 16385
#define DST_OFF (RS_OFF + RS_N)     // 278529

__global__ __launch_bounds__(TPB, 4) void knn_kernel(const float* __restrict__ pts,
                                                     const float* __restrict__ qrs,
                                                     float* __restrict__ out)
{
    // Validated exact-match formula (R6):
    //   sq, sp : forward sum, separate mul/add rounds
    //   ip     : forward FMA chain  fma(z,qz, fma(y,qy, round(x*qx)))
    //   d      : (sq + sp) - 2*ip  == fmaf(-2, ip, sq+sp)  (2*ip exact,
    //            single rounding either way -> bit-identical)
    #pragma clang fp contract(off)

    __shared__ union SmemU {
        float4 tile[TILE];          // 16KB (scan phase)
        float2 merge[K_][TPB];      // 32KB (merge phase)
    } sm;

    const int tid = threadIdx.x;
    const int s   = tid & (SPLIT - 1);
    const int ql  = tid >> 4;                  // 0..15
    const int gq  = blockIdx.x * QPB + ql;     // 0..16383
    const int batch = gq >> 13;                // / 8192
    const int gofs  = batch * NP_;
    const float* pb = pts + (size_t)gofs * 3;

    const float qx = qrs[gq*3+0], qy = qrs[gq*3+1], qz = qrs[gq*3+2];
    const float sq = qx*qx + qy*qy + qz*qz;    // fwd, no FMA (contract off)

    const float INF = __int_as_float(0x7f800000);
    float ad[K_]; int ai[K_];
    #pragma unroll
    for (int i = 0; i < K_; ++i) { ad[i] = INF; ai[i] = 0x7fffffff; }

    // exact distance of tile-local candidate j*16+s (identical chain everywhere)
    auto dof = [&](int j) {
        float4 p = sm.tile[j*SPLIT + s];
        float ip = fmaf(p.z, qz, fmaf(p.y, qy, __fmul_rn(p.x, qx)));
        return fmaf(-2.0f, ip, sq + p.w);
    };

    auto insert1 = [&](float d, int gi) {
        if (d < ad[K_-1]) {                     // strict: stable on ties
            ad[K_-1] = d; ai[K_-1] = gi;
            #pragma unroll
            for (int i = K_-1; i > 0; --i) {
                bool sw = ad[i] < ad[i-1];
                float td = ad[i-1]; int ti = ai[i-1];
                ad[i-1] = sw ? ad[i] : td;  ai[i-1] = sw ? ai[i] : ti;
                ad[i]   = sw ? td   : ad[i]; ai[i]  = sw ? ti   : ai[i];
            }
        }
    };

    auto qmin16 = [&](float w) {               // shared per-query upper bound
        #pragma unroll
        for (int off = 8; off >= 1; off >>= 1)
            w = fminf(w, __shfl_xor(w, off, SPLIT));
        return w;
    };

    float thresh = INF;

    for (int t = 0; t < NTILES; ++t) {
        __syncthreads();
        #pragma unroll
        for (int k = 0; k < TILE/TPB; ++k) {
            int lp = tid + k*TPB;
            int gp = t*TILE + lp;
            float x = pb[gp*3+0], y = pb[gp*3+1], z = pb[gp*3+2];
            float sp = x*x + y*y + z*z;         // fwd, no FMA
            sm.tile[lp] = make_float4(x, y, z, sp);
        }
        __syncthreads();

        // ---- hot scan: register bitmask of passing candidates, no LDS buf ----
        auto scan = [&](int j0) {
            unsigned long long mask = 0ull;
            #pragma unroll 8
            for (int j = j0; j < JPT; ++j) {
                float d = dof(j);
                bool pass = d <= thresh;        // filter key == final key
                if (__any(pass)) {              // rare: v_cmp + scalar branch
                    if (pass) mask |= (1ull << j);
                }
            }
            return mask;
        };

        unsigned long long mask;
        if (t == 0) {
            // seed: first 16 candidates/lane insert unconditionally (uniform)
            for (int j = 0; j < K_; ++j)
                insert1(dof(j), j*SPLIT + s);
            thresh = qmin16(ad[K_-1]);          // finite now
            mask = scan(K_);
        } else {
            mask = scan(0);
        }

        // ---- drain mask bits (ascending j => stable insertion order) ----
        while (mask) {
            int j = __ffsll(mask) - 1;
            mask &= mask - 1;
            insert1(dof(j), t*TILE + j*SPLIT + s);
        }
        thresh = qmin16(ad[K_-1]);
    }

    __syncthreads();      // scan done; reuse LDS for merge lists
    #pragma unroll
    for (int m = 0; m < K_; ++m)
        sm.merge[m][tid] = make_float2(ad[m], __int_as_float(ai[m]));
    __syncthreads();

    // 16-way merge of 16 sorted lists per query via width-16 shfl min-reduce
    int pos = 1;
    float hd = ad[0]; int hi = ai[0];
    float rd = 0.0f;  int ri = 0;
    #pragma unroll
    for (int r = 0; r < K_; ++r) {
        float bd = hd; int bi = hi; int bl = s;
        #pragma unroll
        for (int off = 8; off >= 1; off >>= 1) {
            float od = __shfl_xor(bd, off, SPLIT);
            int   oi = __shfl_xor(bi, off, SPLIT);
            int   ol = __shfl_xor(bl, off, SPLIT);
            bool take = (od < bd) || (od == bd && oi < bi);   // lexicographic: stable
            bd = take ? od : bd; bi = take ? oi : bi; bl = take ? ol : bl;
        }
        if (r == s) { rd = bd; ri = bi; }     // lane s keeps rank-s result
        if (bl == s) {                        // winner advances its head
            if (pos < K_) { float2 e = sm.merge[pos][tid]; hd = e.x; hi = __float_as_int(e.y); ++pos; }
            else { hd = __int_as_float(0x7f800000); hi = 0x7fffffff; }
        }
    }

    // coalesced output: lane s writes rank-s neighbor of its query
    out[IDX_OFF + gq*K_ + s] = (float)(ri + gofs);
    out[DST_OFF + gq*K_ + s] = fmaxf(rd, 0.0f);

    // row_splits = arange(16385) * 16, written as float (exact)
    int gt = blockIdx.x * TPB + tid;
    if (gt < RS_N) out[RS_OFF + gt] = (float)(gt * K_);
}

extern "C" void kernel_launch(void* const* d_in, const int* in_sizes, int n_in,
                              void* d_out, int out_size, void* d_ws, size_t ws_size,
                              hipStream_t stream)
{
    const float* pts = (const float*)d_in[0];
    const float* qrs = (const float*)d_in[1];
    float* out = (float*)d_out;
    (void)in_sizes; (void)n_in; (void)out_size; (void)d_ws; (void)ws_size;

    dim3 grid(NB_ * NQ_ / QPB);   // 1024 blocks
    dim3 block(TPB);              // 256 threads
    knn_kernel<<<grid, block, 0, stream>>>(pts, qrs, out);
}